// Round 6
// baseline (898.301 us; speedup 1.0000x reference)
//
#include <hip/hip_runtime.h>
#include <hip/hip_fp16.h>
#include <math.h>

#define NNODE 50000
#define NEDGE 800000
#define FIN 128
#define EDIM 64
#define HC 256
#define NH 4
#define CC 64
#define SCAN_TILE 512
#define EB 128   // edges per block in k_elog_both

typedef _Float16 half8v __attribute__((ext_vector_type(8)));
typedef _Float16 half4v __attribute__((ext_vector_type(4)));
typedef float floatx4 __attribute__((ext_vector_type(4)));

// ---------------- CSR build (dst -> incoming edge list) ----------------
__global__ void k_count(const int* __restrict__ dst, int* counts, int E) {
    int e = blockIdx.x * 256 + threadIdx.x;
    if (e < E) atomicAdd(&counts[dst[e]], 1);
}

__global__ void k_scan1(const int* __restrict__ counts, int* offs, int* tilesums, int N) {
    __shared__ int s[SCAN_TILE];
    int t = threadIdx.x;
    int i = blockIdx.x * SCAN_TILE + t;
    int v = (i < N) ? counts[i] : 0;
    s[t] = v;
    for (int off = 1; off < SCAN_TILE; off <<= 1) {
        __syncthreads();
        int x = (t >= off) ? s[t - off] : 0;
        __syncthreads();
        s[t] += x;
    }
    __syncthreads();
    if (i < N) offs[i] = s[t] - v;  // exclusive within tile
    if (t == SCAN_TILE - 1) tilesums[blockIdx.x] = s[t];
}

__global__ void k_scan2(int* tilesums, int nt) {
    if (threadIdx.x == 0) {
        int run = 0;
        for (int i = 0; i < nt; i++) { int v = tilesums[i]; tilesums[i] = run; run += v; }
    }
}

__global__ void k_scan3(int* offs, const int* __restrict__ tilesums, int N, int E) {
    int t = threadIdx.x;
    int i = blockIdx.x * SCAN_TILE + t;
    if (i < N) offs[i] += tilesums[blockIdx.x];
    if (i == 0) offs[N] = E;
}

__global__ void k_fill(const int* __restrict__ src, const int* __restrict__ dst,
                       const int* __restrict__ offs, int* cursor,
                       int* elist, int* slist, int E) {
    int e = blockIdx.x * 256 + threadIdx.x;
    if (e < E) {
        int d = dst[e];
        int pos = offs[d] + atomicAdd(&cursor[d], 1);
        elist[pos] = e;
        slist[pos] = src[e];
    }
}

__device__ inline float4 h4_to_f4(uint2 r) {
    float2 fa = __half22float2(*(__half2*)&r.x);
    float2 fb = __half22float2(*(__half2*)&r.y);
    return make_float4(fa.x, fa.y, fb.x, fb.y);
}

__device__ inline float sel_h(float4 v, int head) {
    return head == 0 ? v.x : head == 1 ? v.y : head == 2 ? v.z : v.w;
}

// W[K,256] fp32 -> Wt[256,K] fp16 (transpose); grid=K, block=256
__global__ void k_castW(const float* __restrict__ W, _Float16* __restrict__ Wt, int K) {
    int k = blockIdx.x, n = threadIdx.x;
    Wt[(size_t)n * K + k] = (_Float16)W[(size_t)k * HC + n];
}

// ---------------- fp16 MFMA GEMM + fused avec epilogue ----------------
// H16[M,256] = A[M,K] @ Wt16^T ; asrc/adst[row,h] = sum_c h*att
// wave = 16 rows x 256 cols (16 acc tiles), block = 4 waves = 64 rows
template <typename AT>
__global__ __launch_bounds__(256) void k_gemm_mfma(const AT* __restrict__ A,
                                                   const _Float16* __restrict__ Wt16,
                                                   _Float16* __restrict__ H16,
                                                   const float* __restrict__ att_s,
                                                   const float* __restrict__ att_d,
                                                   float* __restrict__ asrc,
                                                   float* __restrict__ adst,
                                                   int M, int K) {
    int wave = threadIdx.x >> 6, lane = threadIdx.x & 63;
    int quad = lane >> 4, l16 = lane & 15;
    int row = blockIdx.x * 64 + wave * 16 + l16;     // A-frag row (m = lane&15)
    bool rok = row < M;
    floatx4 acc[16];
#pragma unroll
    for (int i = 0; i < 16; i++) acc[i] = (floatx4)(0.0f);
    int nk = K >> 5;
    for (int kk = 0; kk < nk; kk++) {
        half8v a = {};
        if (rok) {
            if constexpr (sizeof(AT) == 2) {
                a = *(const half8v*)(A + (size_t)row * K + kk * 32 + quad * 8);
            } else {
                const float* ap = (const float*)A + (size_t)row * K + kk * 32 + quad * 8;
                float4 v0 = *(const float4*)ap;
                float4 v1 = *(const float4*)(ap + 4);
                a[0] = (_Float16)v0.x; a[1] = (_Float16)v0.y;
                a[2] = (_Float16)v0.z; a[3] = (_Float16)v0.w;
                a[4] = (_Float16)v1.x; a[5] = (_Float16)v1.y;
                a[6] = (_Float16)v1.z; a[7] = (_Float16)v1.w;
            }
        }
#pragma unroll
        for (int nt = 0; nt < 16; nt++) {
            half8v b = *(const half8v*)(Wt16 + (size_t)(nt * 16 + l16) * K + kk * 32 + quad * 8);
            acc[nt] = __builtin_amdgcn_mfma_f32_16x16x32_f16(a, b, acc[nt], 0, 0, 0);
        }
    }
    // ---- avec epilogue: lane holds rows quad*4+r, cols nt*16+l16 ----
    float asl[16], adl[16];
#pragma unroll
    for (int nt = 0; nt < 16; nt++) {
        asl[nt] = att_s[nt * 16 + l16];
        adl[nt] = att_d[nt * 16 + l16];
    }
    int orow0 = blockIdx.x * 64 + wave * 16 + quad * 4;
#pragma unroll
    for (int r = 0; r < 4; r++) {
        float vs = 0.f, vd = 0.f;
#pragma unroll
        for (int nt = 0; nt < 16; nt++) {
            float hv = acc[nt][r];
            vs += hv * asl[nt];
            vd += hv * adl[nt];
        }
        // reduce over the 16 lanes of this quad (per head piece is embedded: cols are flat h*64+c)
        vs += __shfl_xor(vs, 1, 64); vd += __shfl_xor(vd, 1, 64);
        vs += __shfl_xor(vs, 2, 64); vd += __shfl_xor(vd, 2, 64);
        vs += __shfl_xor(vs, 4, 64); vd += __shfl_xor(vd, 4, 64);
        // now lanes l16%8==x hold partials over pairs... careful: we need per-head sums.
        // cols nt*16+l16: head = col>>6 = (nt*16+l16)>>6 = nt>>2. So each lane's vs above
        // mixed ALL heads -- wrong. Recompute per-head instead below.
        (void)vs; (void)vd;
    }
    // ---- correct per-head avec: head h covers nt in [h*4, h*4+4) ----
#pragma unroll
    for (int r = 0; r < 4; r++) {
        int orow = orow0 + r;
        float4 vs4, vd4;
        float* vsp = (float*)&vs4;
        float* vdp = (float*)&vd4;
#pragma unroll
        for (int hh = 0; hh < 4; hh++) {
            float vs = 0.f, vd = 0.f;
#pragma unroll
            for (int q = 0; q < 4; q++) {
                int nt = hh * 4 + q;
                float hv = acc[nt][r];
                vs += hv * asl[nt];
                vd += hv * adl[nt];
            }
            vs += __shfl_xor(vs, 1, 64); vd += __shfl_xor(vd, 1, 64);
            vs += __shfl_xor(vs, 2, 64); vd += __shfl_xor(vd, 2, 64);
            vs += __shfl_xor(vs, 4, 64); vd += __shfl_xor(vd, 4, 64);
            vs += __shfl_xor(vs, 8, 64); vd += __shfl_xor(vd, 8, 64);
            vsp[hh] = vs; vdp[hh] = vd;
        }
        if (l16 == 0 && orow < M) {
            ((float4*)asrc)[orow] = vs4;
            ((float4*)adst)[orow] = vd4;
        }
    }
    // ---- store h16 ----
#pragma unroll
    for (int r = 0; r < 4; r++) {
        int orow = orow0 + r;
        if (orow < M) {
#pragma unroll
            for (int nt = 0; nt < 16; nt++)
                H16[(size_t)orow * HC + nt * 16 + l16] = (_Float16)acc[nt][r];
        }
    }
}

// ---------------- we_att[d,h] = sum_c edgeW[d, h*64+c] * att_e[h,c] ----------------
__global__ void k_weatt(const float* __restrict__ edgeW, const float* __restrict__ att_e,
                        float* we) {
    int t = threadIdx.x;
    int d = t >> 2, hh = t & 3;
    float s = 0.f;
    for (int c = 0; c < 64; c++) s += edgeW[d * HC + hh * 64 + c] * att_e[hh * 64 + c];
    we[d * 4 + hh] = s;
}

// ---------------- elog{1,2}[e,h] = edge_feat[e,:] . we{1,2}[:,h]  (both layers, one ef pass) ----
__global__ __launch_bounds__(128) void k_elog_both(const float* __restrict__ ef,
                                                   const float* __restrict__ we1,
                                                   const float* __restrict__ we2,
                                                   float* __restrict__ elog1,
                                                   float* __restrict__ elog2, int E) {
    __shared__ float sEf[EB][65];
    int t = threadIdx.x;
    int e0 = blockIdx.x * EB;
    for (int i = 0; i < 16; i++) {
        int q = t + i * 128;
        int le = q >> 4, c4 = (q & 15) << 2;
        int ge = e0 + le;
        float4 v = make_float4(0.f, 0.f, 0.f, 0.f);
        if (ge < E) v = *(const float4*)(ef + (size_t)ge * EDIM + c4);
        sEf[le][c4 + 0] = v.x; sEf[le][c4 + 1] = v.y;
        sEf[le][c4 + 2] = v.z; sEf[le][c4 + 3] = v.w;
    }
    __syncthreads();
    float a1[4] = {}, a2[4] = {};
#pragma unroll 8
    for (int c = 0; c < 64; c++) {
        float v = sEf[t][c];
        float4 w1 = *(const float4*)(we1 + c * 4);
        float4 w2 = *(const float4*)(we2 + c * 4);
        a1[0] += v * w1.x; a1[1] += v * w1.y; a1[2] += v * w1.z; a1[3] += v * w1.w;
        a2[0] += v * w2.x; a2[1] += v * w2.y; a2[2] += v * w2.z; a2[3] += v * w2.w;
    }
    int e = e0 + t;
    if (e < E) {
        ((float4*)elog1)[e] = make_float4(a1[0], a1[1], a1[2], a1[3]);
        ((float4*)elog2)[e] = make_float4(a2[0], a2[1], a2[2], a2[3]);
    }
}

// ---------------- fused aggregation: p + pself + weighted gather, wave/node ----------------
// LAYER 1 writes fp16 x2 (GEMM input); LAYER 2 writes fp32 final out.
template <int LAYER>
__global__ __launch_bounds__(256) void k_aggr(const _Float16* __restrict__ hb,
                                              const float* __restrict__ elog,
                                              const float* __restrict__ asrc,
                                              const float* __restrict__ adst,
                                              const int* __restrict__ offs,
                                              const int* __restrict__ elist,
                                              const int* __restrict__ slist,
                                              const float* __restrict__ bias,
                                              _Float16* __restrict__ out16,
                                              float* __restrict__ out32, int N) {
    int wave = threadIdx.x >> 6, lane = threadIdx.x & 63;
    int n = blockIdx.x * 4 + wave;
    if (n >= N) return;
    int head = lane >> 4;
    const uint2* hf = (const uint2*)hb;     // 4 halves per entry, 64 entries per row
    int beg = offs[n], end = offs[n + 1];

    float4 adn = ((const float4*)adst)[n];
    float adh = sel_h(adn, head);
    float4 sum_el = make_float4(0.f, 0.f, 0.f, 0.f);
    float denom = 0.f, ax = 0.f, ay = 0.f, az = 0.f, aw = 0.f;

    int i = beg;
    for (; i + 8 <= end; i += 8) {
        int e[8], s[8];
#pragma unroll
        for (int j = 0; j < 8; j++) e[j] = elist[i + j];
#pragma unroll
        for (int j = 0; j < 8; j++) s[j] = slist[i + j];
        float4 el[8];
        float4 as4[8];
        uint2 r[8];
#pragma unroll
        for (int j = 0; j < 8; j++) el[j] = ((const float4*)elog)[e[j]];
#pragma unroll
        for (int j = 0; j < 8; j++) as4[j] = ((const float4*)asrc)[s[j]];
#pragma unroll
        for (int j = 0; j < 8; j++) r[j] = hf[(size_t)s[j] * 64 + lane];
#pragma unroll
        for (int j = 0; j < 8; j++) {
            sum_el.x += el[j].x; sum_el.y += el[j].y;
            sum_el.z += el[j].z; sum_el.w += el[j].w;
            float lg = sel_h(as4[j], head) + adh + sel_h(el[j], head);
            lg = lg > 0.f ? lg : 0.2f * lg;
            float w = expf(lg);
            denom += w;
            float4 h4 = h4_to_f4(r[j]);
            ax += w * h4.x; ay += w * h4.y; az += w * h4.z; aw += w * h4.w;
        }
    }
    for (; i < end; i++) {
        int e0i = elist[i], s0 = slist[i];
        float4 el = ((const float4*)elog)[e0i];
        float4 as4 = ((const float4*)asrc)[s0];
        uint2 r = hf[(size_t)s0 * 64 + lane];
        sum_el.x += el.x; sum_el.y += el.y; sum_el.z += el.z; sum_el.w += el.w;
        float lg = sel_h(as4, head) + adh + sel_h(el, head);
        lg = lg > 0.f ? lg : 0.2f * lg;
        float w = expf(lg);
        denom += w;
        float4 h4 = h4_to_f4(r);
        ax += w * h4.x; ay += w * h4.y; az += w * h4.z; aw += w * h4.w;
    }

    // self loop: attr = mean of incoming elog
    float cnt = (float)(end - beg);
    if (cnt < 1.f) cnt = 1.f;
    float4 asn = ((const float4*)asrc)[n];
    float lg = sel_h(asn, head) + adh + sel_h(sum_el, head) / cnt;
    lg = lg > 0.f ? lg : 0.2f * lg;
    float ps = expf(lg);
    denom += ps;
    float4 hvn = h4_to_f4(hf[(size_t)n * 64 + lane]);
    ax += ps * hvn.x; ay += ps * hvn.y; az += ps * hvn.z; aw += ps * hvn.w;

    float inv = 1.0f / (denom + 1e-16f);
    ax *= inv; ay *= inv; az *= inv; aw *= inv;

    if (LAYER == 1) {
        float4 bv = ((const float4*)bias)[lane];
        half4v o;
        float v;
        v = ax + bv.x; o[0] = (_Float16)(v > 0.f ? v : expf(v) - 1.0f);
        v = ay + bv.y; o[1] = (_Float16)(v > 0.f ? v : expf(v) - 1.0f);
        v = az + bv.z; o[2] = (_Float16)(v > 0.f ? v : expf(v) - 1.0f);
        v = aw + bv.w; o[3] = (_Float16)(v > 0.f ? v : expf(v) - 1.0f);
        ((half4v*)(out16 + (size_t)n * HC))[lane] = o;
    } else {
        // mean over heads: reduce lanes {l, l^16, l^32, l^48}
        ax += __shfl_xor(ax, 16, 64); ax += __shfl_xor(ax, 32, 64);
        ay += __shfl_xor(ay, 16, 64); ay += __shfl_xor(ay, 32, 64);
        az += __shfl_xor(az, 16, 64); az += __shfl_xor(az, 32, 64);
        aw += __shfl_xor(aw, 16, 64); aw += __shfl_xor(aw, 32, 64);
        if (lane < 16) {
            float4 bv = ((const float4*)bias)[lane];
            float4 o;
            o.x = 0.25f * ax + bv.x;
            o.y = 0.25f * ay + bv.y;
            o.z = 0.25f * az + bv.z;
            o.w = 0.25f * aw + bv.w;
            ((float4*)(out32 + (size_t)n * CC))[lane] = o;
        }
    }
}

extern "C" void kernel_launch(void* const* d_in, const int* in_sizes, int n_in,
                              void* d_out, int out_size, void* d_ws, size_t ws_size,
                              hipStream_t stream) {
    const float* x   = (const float*)d_in[0];
    const float* ef  = (const float*)d_in[1];
    const int*   ei  = (const int*)d_in[2];
    const float* W1  = (const float*)d_in[3];
    const float* as1 = (const float*)d_in[4];
    const float* ad1 = (const float*)d_in[5];
    const float* ae1 = (const float*)d_in[6];
    const float* b1  = (const float*)d_in[7];
    const float* eW1 = (const float*)d_in[8];
    const float* W2  = (const float*)d_in[9];
    const float* as2 = (const float*)d_in[10];
    const float* ad2 = (const float*)d_in[11];
    const float* ae2 = (const float*)d_in[12];
    const float* b2  = (const float*)d_in[13];
    const float* eW2 = (const float*)d_in[14];
    float* out = (float*)d_out;
    const int* srcp = ei;
    const int* dstp = ei + NEDGE;

    char* w = (char*)d_ws;
    auto alloc = [&](size_t bytes) -> char* {
        char* r = w;
        w += (bytes + 255) / 256 * 256;
        return r;
    };
    _Float16* hb16  = (_Float16*)alloc((size_t)NNODE * HC * 2);   // h (fp16, both layers)
    _Float16* x216  = (_Float16*)alloc((size_t)NNODE * HC * 2);   // layer-2 GEMM input
    _Float16* wt1   = (_Float16*)alloc((size_t)HC * FIN * 2);     // W1^T fp16
    _Float16* wt2   = (_Float16*)alloc((size_t)HC * HC * 2);      // W2^T fp16
    float* elog1  = (float*)alloc((size_t)NEDGE * 4 * 4);
    float* elog2  = (float*)alloc((size_t)NEDGE * 4 * 4);
    float* asrc   = (float*)alloc((size_t)NNODE * 4 * 4);
    float* adst   = (float*)alloc((size_t)NNODE * 4 * 4);
    float* webuf1 = (float*)alloc(64 * 4 * 4);
    float* webuf2 = (float*)alloc(64 * 4 * 4);
    int* counts  = (int*)alloc((size_t)NNODE * 4);
    int* offs    = (int*)alloc((size_t)(NNODE + 1) * 4);
    int* tiles   = (int*)alloc(1024 * 4);
    int* cursor  = (int*)alloc((size_t)NNODE * 4);
    int* elist   = (int*)alloc((size_t)NEDGE * 4);
    int* slist   = (int*)alloc((size_t)NEDGE * 4);

    hipMemsetAsync(counts, 0, (size_t)NNODE * 4, stream);
    hipMemsetAsync(cursor, 0, (size_t)NNODE * 4, stream);

    // CSR build (shared by both layers)
    k_count<<<(NEDGE + 255) / 256, 256, 0, stream>>>(dstp, counts, NEDGE);
    int nt = (NNODE + SCAN_TILE - 1) / SCAN_TILE;
    k_scan1<<<nt, SCAN_TILE, 0, stream>>>(counts, offs, tiles, NNODE);
    k_scan2<<<1, 64, 0, stream>>>(tiles, nt);
    k_scan3<<<nt, SCAN_TILE, 0, stream>>>(offs, tiles, NNODE, NEDGE);
    k_fill<<<(NEDGE + 255) / 256, 256, 0, stream>>>(srcp, dstp, offs, cursor, elist, slist, NEDGE);

    // fp16 weight transposes
    k_castW<<<FIN, 256, 0, stream>>>(W1, wt1, FIN);
    k_castW<<<HC, 256, 0, stream>>>(W2, wt2, HC);

    // edge logits for BOTH layers in one pass over ef
    k_weatt<<<1, 256, 0, stream>>>(eW1, ae1, webuf1);
    k_weatt<<<1, 256, 0, stream>>>(eW2, ae2, webuf2);
    k_elog_both<<<(NEDGE + EB - 1) / EB, EB, 0, stream>>>(ef, webuf1, webuf2, elog1, elog2, NEDGE);

    // ---- layer 1 ----
    k_gemm_mfma<float><<<(NNODE + 63) / 64, 256, 0, stream>>>(x, wt1, hb16, as1, ad1, asrc, adst, NNODE, FIN);
    k_aggr<1><<<(NNODE + 3) / 4, 256, 0, stream>>>(hb16, elog1, asrc, adst, offs, elist, slist, b1, x216, nullptr, NNODE);

    // ---- layer 2 ----
    k_gemm_mfma<_Float16><<<(NNODE + 63) / 64, 256, 0, stream>>>(x216, wt2, hb16, as2, ad2, asrc, adst, NNODE, HC);
    k_aggr<2><<<(NNODE + 3) / 4, 256, 0, stream>>>(hb16, elog2, asrc, adst, offs, elist, slist, b2, nullptr, out, NNODE);
}

// Round 7
// 807.796 us; speedup vs baseline: 1.1120x; 1.1120x over previous
//
#include <hip/hip_runtime.h>
#include <hip/hip_fp16.h>
#include <math.h>

#define NNODE 50000
#define NEDGE 800000
#define FIN 128
#define EDIM 64
#define HC 256
#define NH 4
#define CC 64
#define SCAN_TILE 512
#define EB 128   // edges per block in k_elog_both

typedef _Float16 half8v __attribute__((ext_vector_type(8)));
typedef _Float16 half4v __attribute__((ext_vector_type(4)));
typedef float floatx4 __attribute__((ext_vector_type(4)));

// ---------------- CSR build (dst -> incoming edge list) ----------------
__global__ void k_count(const int* __restrict__ dst, int* counts, int E) {
    int e = blockIdx.x * 256 + threadIdx.x;
    if (e < E) atomicAdd(&counts[dst[e]], 1);
}

__global__ void k_scan1(const int* __restrict__ counts, int* offs, int* tilesums, int N) {
    __shared__ int s[SCAN_TILE];
    int t = threadIdx.x;
    int i = blockIdx.x * SCAN_TILE + t;
    int v = (i < N) ? counts[i] : 0;
    s[t] = v;
    for (int off = 1; off < SCAN_TILE; off <<= 1) {
        __syncthreads();
        int x = (t >= off) ? s[t - off] : 0;
        __syncthreads();
        s[t] += x;
    }
    __syncthreads();
    if (i < N) offs[i] = s[t] - v;  // exclusive within tile
    if (t == SCAN_TILE - 1) tilesums[blockIdx.x] = s[t];
}

__global__ void k_scan2(int* tilesums, int nt) {
    if (threadIdx.x == 0) {
        int run = 0;
        for (int i = 0; i < nt; i++) { int v = tilesums[i]; tilesums[i] = run; run += v; }
    }
}

__global__ void k_scan3(int* offs, const int* __restrict__ tilesums, int N, int E) {
    int t = threadIdx.x;
    int i = blockIdx.x * SCAN_TILE + t;
    if (i < N) offs[i] += tilesums[blockIdx.x];
    if (i == 0) offs[N] = E;
}

// es[pos] = {edge_id, src} -- single 8B scattered write
__global__ void k_fill(const int* __restrict__ src, const int* __restrict__ dst,
                       const int* __restrict__ offs, int* cursor,
                       int2* __restrict__ es, int E) {
    int e = blockIdx.x * 256 + threadIdx.x;
    if (e < E) {
        int d = dst[e];
        int pos = offs[d] + atomicAdd(&cursor[d], 1);
        es[pos] = make_int2(e, src[e]);
    }
}

__device__ inline float4 h4_to_f4(uint2 r) {
    float2 fa = __half22float2(*(__half2*)&r.x);
    float2 fb = __half22float2(*(__half2*)&r.y);
    return make_float4(fa.x, fa.y, fb.x, fb.y);
}

__device__ inline float sel_h(float4 v, int head) {
    return head == 0 ? v.x : head == 1 ? v.y : head == 2 ? v.z : v.w;
}

// W[K,256] fp32 -> Wt[256,K] fp16 (transpose); grid=K, block=256
__global__ void k_castW(const float* __restrict__ W, _Float16* __restrict__ Wt, int K) {
    int k = blockIdx.x, n = threadIdx.x;
    Wt[(size_t)n * K + k] = (_Float16)W[(size_t)k * HC + n];
}

// ---------------- fp16 MFMA GEMM + fused avec epilogue ----------------
// H16[M,256] = A[M,K] @ Wt16^T ; asrc/adst[row,h] = sum_c h[row,h,c]*att[h,c]
// wave = 16 rows x 256 cols (16 acc tiles), block = 4 waves = 64 rows
template <typename AT>
__global__ __launch_bounds__(256) void k_gemm_mfma(const AT* __restrict__ A,
                                                   const _Float16* __restrict__ Wt16,
                                                   _Float16* __restrict__ H16,
                                                   const float* __restrict__ att_s,
                                                   const float* __restrict__ att_d,
                                                   float* __restrict__ asrc,
                                                   float* __restrict__ adst,
                                                   int M, int K) {
    int wave = threadIdx.x >> 6, lane = threadIdx.x & 63;
    int quad = lane >> 4, l16 = lane & 15;
    int row = blockIdx.x * 64 + wave * 16 + l16;     // A-frag row (m = lane&15)
    bool rok = row < M;
    floatx4 acc[16];
#pragma unroll
    for (int i = 0; i < 16; i++) acc[i] = (floatx4)(0.0f);
    int nk = K >> 5;
    for (int kk = 0; kk < nk; kk++) {
        half8v a = {};
        if (rok) {
            if constexpr (sizeof(AT) == 2) {
                a = *(const half8v*)(A + (size_t)row * K + kk * 32 + quad * 8);
            } else {
                const float* ap = (const float*)A + (size_t)row * K + kk * 32 + quad * 8;
                float4 v0 = *(const float4*)ap;
                float4 v1 = *(const float4*)(ap + 4);
                a[0] = (_Float16)v0.x; a[1] = (_Float16)v0.y;
                a[2] = (_Float16)v0.z; a[3] = (_Float16)v0.w;
                a[4] = (_Float16)v1.x; a[5] = (_Float16)v1.y;
                a[6] = (_Float16)v1.z; a[7] = (_Float16)v1.w;
            }
        }
#pragma unroll
        for (int nt = 0; nt < 16; nt++) {
            half8v b = *(const half8v*)(Wt16 + (size_t)(nt * 16 + l16) * K + kk * 32 + quad * 8);
            acc[nt] = __builtin_amdgcn_mfma_f32_16x16x32_f16(a, b, acc[nt], 0, 0, 0);
        }
    }
    // lane holds rows quad*4+r (r=0..3), cols nt*16+l16; head of col = nt>>2
    float asl[16], adl[16];
#pragma unroll
    for (int nt = 0; nt < 16; nt++) {
        asl[nt] = att_s[nt * 16 + l16];
        adl[nt] = att_d[nt * 16 + l16];
    }
    int orow0 = blockIdx.x * 64 + wave * 16 + quad * 4;
#pragma unroll
    for (int r = 0; r < 4; r++) {
        int orow = orow0 + r;
        float4 vs4, vd4;
        float* vsp = (float*)&vs4;
        float* vdp = (float*)&vd4;
#pragma unroll
        for (int hh = 0; hh < 4; hh++) {
            float vs = 0.f, vd = 0.f;
#pragma unroll
            for (int q = 0; q < 4; q++) {
                int nt = hh * 4 + q;
                float hv = acc[nt][r];
                vs += hv * asl[nt];
                vd += hv * adl[nt];
            }
            vs += __shfl_xor(vs, 1, 64); vd += __shfl_xor(vd, 1, 64);
            vs += __shfl_xor(vs, 2, 64); vd += __shfl_xor(vd, 2, 64);
            vs += __shfl_xor(vs, 4, 64); vd += __shfl_xor(vd, 4, 64);
            vs += __shfl_xor(vs, 8, 64); vd += __shfl_xor(vd, 8, 64);
            vsp[hh] = vs; vdp[hh] = vd;
        }
        if (l16 == 0 && orow < M) {
            ((float4*)asrc)[orow] = vs4;
            ((float4*)adst)[orow] = vd4;
        }
    }
#pragma unroll
    for (int r = 0; r < 4; r++) {
        int orow = orow0 + r;
        if (orow < M) {
#pragma unroll
            for (int nt = 0; nt < 16; nt++)
                H16[(size_t)orow * HC + nt * 16 + l16] = (_Float16)acc[nt][r];
        }
    }
}

// ---------------- we_att[d,h] = sum_c edgeW[d, h*64+c] * att_e[h,c] ----------------
__global__ void k_weatt(const float* __restrict__ edgeW, const float* __restrict__ att_e,
                        float* we) {
    int t = threadIdx.x;
    int d = t >> 2, hh = t & 3;
    float s = 0.f;
    for (int c = 0; c < 64; c++) s += edgeW[d * HC + hh * 64 + c] * att_e[hh * 64 + c];
    we[d * 4 + hh] = s;
}

// ---------------- elog{1,2}[e,h] = edge_feat[e,:] . we{1,2}[:,h]  (both layers, one ef pass) ----
__global__ __launch_bounds__(128) void k_elog_both(const float* __restrict__ ef,
                                                   const float* __restrict__ we1,
                                                   const float* __restrict__ we2,
                                                   float* __restrict__ elog1,
                                                   float* __restrict__ elog2, int E) {
    __shared__ float sEf[EB][65];
    int t = threadIdx.x;
    int e0 = blockIdx.x * EB;
    for (int i = 0; i < 16; i++) {
        int q = t + i * 128;
        int le = q >> 4, c4 = (q & 15) << 2;
        int ge = e0 + le;
        float4 v = make_float4(0.f, 0.f, 0.f, 0.f);
        if (ge < E) v = *(const float4*)(ef + (size_t)ge * EDIM + c4);
        sEf[le][c4 + 0] = v.x; sEf[le][c4 + 1] = v.y;
        sEf[le][c4 + 2] = v.z; sEf[le][c4 + 3] = v.w;
    }
    __syncthreads();
    float a1[4] = {}, a2[4] = {};
#pragma unroll 8
    for (int c = 0; c < 64; c++) {
        float v = sEf[t][c];
        float4 w1 = *(const float4*)(we1 + c * 4);
        float4 w2 = *(const float4*)(we2 + c * 4);
        a1[0] += v * w1.x; a1[1] += v * w1.y; a1[2] += v * w1.z; a1[3] += v * w1.w;
        a2[0] += v * w2.x; a2[1] += v * w2.y; a2[2] += v * w2.z; a2[3] += v * w2.w;
    }
    int e = e0 + t;
    if (e < E) {
        ((float4*)elog1)[e] = make_float4(a1[0], a1[1], a1[2], a1[3]);
        ((float4*)elog2)[e] = make_float4(a2[0], a2[1], a2[2], a2[3]);
    }
}

// ---------------- per-edge p in CSR order + pself, one node-parallel pass ----------------
// wave per node: lanes sweep CSR range; pcsr written sequentially; elog segment-sum
// wave-reduced for the self-loop numerator.
__global__ __launch_bounds__(256) void k_pedge(const float* __restrict__ elog,
                                               const float* __restrict__ asrc,
                                               const float* __restrict__ adst,
                                               const int* __restrict__ offs,
                                               const int2* __restrict__ es,
                                               float* __restrict__ pcsr,
                                               float* __restrict__ pself, int N) {
    int wave = threadIdx.x >> 6, lane = threadIdx.x & 63;
    int n = blockIdx.x * 4 + wave;
    if (n >= N) return;
    int beg = offs[n], end = offs[n + 1];
    float4 adn = ((const float4*)adst)[n];
    float s0 = 0.f, s1 = 0.f, s2 = 0.f, s3 = 0.f;
    for (int i0 = beg; i0 < end; i0 += 64) {
        int i = i0 + lane;
        if (i < end) {
            int2 e = es[i];
            float4 el = ((const float4*)elog)[e.x];
            float4 as4 = ((const float4*)asrc)[e.y];
            s0 += el.x; s1 += el.y; s2 += el.z; s3 += el.w;
            float4 o;
            float l;
            l = as4.x + adn.x + el.x; l = l > 0.f ? l : 0.2f * l; o.x = expf(l);
            l = as4.y + adn.y + el.y; l = l > 0.f ? l : 0.2f * l; o.y = expf(l);
            l = as4.z + adn.z + el.z; l = l > 0.f ? l : 0.2f * l; o.z = expf(l);
            l = as4.w + adn.w + el.w; l = l > 0.f ? l : 0.2f * l; o.w = expf(l);
            ((float4*)pcsr)[i] = o;
        }
    }
    for (int m = 32; m >= 1; m >>= 1) {
        s0 += __shfl_xor(s0, m, 64);
        s1 += __shfl_xor(s1, m, 64);
        s2 += __shfl_xor(s2, m, 64);
        s3 += __shfl_xor(s3, m, 64);
    }
    if (lane == 0) {
        float cnt = (float)(end - beg);
        if (cnt < 1.f) cnt = 1.f;
        float4 asn = ((const float4*)asrc)[n];
        float4 o;
        float l;
        l = asn.x + adn.x + s0 / cnt; l = l > 0.f ? l : 0.2f * l; o.x = expf(l);
        l = asn.y + adn.y + s1 / cnt; l = l > 0.f ? l : 0.2f * l; o.y = expf(l);
        l = asn.z + adn.z + s2 / cnt; l = l > 0.f ? l : 0.2f * l; o.z = expf(l);
        l = asn.w + adn.w + s3 / cnt; l = l > 0.f ? l : 0.2f * l; o.w = expf(l);
        ((float4*)pself)[n] = o;
    }
}

// ---------------- aggregation: wave/node, lane/(4 flat channels), fp16 gather ----------------
// Sequential pcsr + es reads; only random stream is the h row gather.
template <int LAYER>
__global__ __launch_bounds__(256) void k_aggr(const _Float16* __restrict__ hb,
                                              const float* __restrict__ pcsr,
                                              const float* __restrict__ pself,
                                              const int* __restrict__ offs,
                                              const int2* __restrict__ es,
                                              const float* __restrict__ bias,
                                              _Float16* __restrict__ out16,
                                              float* __restrict__ out32, int N) {
    int wave = threadIdx.x >> 6, lane = threadIdx.x & 63;
    int n = blockIdx.x * 4 + wave;
    if (n >= N) return;
    int head = lane >> 4;
    const uint2* hf = (const uint2*)hb;     // 4 halves per entry, 64 entries per row
    const float4* pc = (const float4*)pcsr;
    int beg = offs[n], end = offs[n + 1];

    float4 ps4 = ((const float4*)pself)[n];
    float ps = sel_h(ps4, head);
    float4 hv = h4_to_f4(hf[(size_t)n * 64 + lane]);
    float denom = ps;
    float ax = ps * hv.x, ay = ps * hv.y, az = ps * hv.z, aw = ps * hv.w;

    int i = beg;
    for (; i + 8 <= end; i += 8) {
        int s[8];
        uint2 r[8];
        float4 p[8];
#pragma unroll
        for (int j = 0; j < 8; j++) s[j] = es[i + j].y;
#pragma unroll
        for (int j = 0; j < 8; j++) r[j] = hf[(size_t)s[j] * 64 + lane];
#pragma unroll
        for (int j = 0; j < 8; j++) p[j] = pc[i + j];
#pragma unroll
        for (int j = 0; j < 8; j++) {
            float w = sel_h(p[j], head);
            float4 h4 = h4_to_f4(r[j]);
            denom += w;
            ax += w * h4.x; ay += w * h4.y; az += w * h4.z; aw += w * h4.w;
        }
    }
    for (; i < end; i++) {
        int s0 = es[i].y;
        float4 p0 = pc[i];
        float4 h4 = h4_to_f4(hf[(size_t)s0 * 64 + lane]);
        float w0 = sel_h(p0, head);
        denom += w0;
        ax += w0 * h4.x; ay += w0 * h4.y; az += w0 * h4.z; aw += w0 * h4.w;
    }
    float inv = 1.0f / (denom + 1e-16f);
    ax *= inv; ay *= inv; az *= inv; aw *= inv;

    if (LAYER == 1) {
        float4 bv = ((const float4*)bias)[lane];
        half4v o;
        float v;
        v = ax + bv.x; o[0] = (_Float16)(v > 0.f ? v : expf(v) - 1.0f);
        v = ay + bv.y; o[1] = (_Float16)(v > 0.f ? v : expf(v) - 1.0f);
        v = az + bv.z; o[2] = (_Float16)(v > 0.f ? v : expf(v) - 1.0f);
        v = aw + bv.w; o[3] = (_Float16)(v > 0.f ? v : expf(v) - 1.0f);
        ((half4v*)(out16 + (size_t)n * HC))[lane] = o;
    } else {
        // mean over heads: reduce lanes {l, l^16, l^32, l^48}
        ax += __shfl_xor(ax, 16, 64); ax += __shfl_xor(ax, 32, 64);
        ay += __shfl_xor(ay, 16, 64); ay += __shfl_xor(ay, 32, 64);
        az += __shfl_xor(az, 16, 64); az += __shfl_xor(az, 32, 64);
        aw += __shfl_xor(aw, 16, 64); aw += __shfl_xor(aw, 32, 64);
        if (lane < 16) {
            float4 bv = ((const float4*)bias)[lane];
            float4 o;
            o.x = 0.25f * ax + bv.x;
            o.y = 0.25f * ay + bv.y;
            o.z = 0.25f * az + bv.z;
            o.w = 0.25f * aw + bv.w;
            ((float4*)(out32 + (size_t)n * CC))[lane] = o;
        }
    }
}

extern "C" void kernel_launch(void* const* d_in, const int* in_sizes, int n_in,
                              void* d_out, int out_size, void* d_ws, size_t ws_size,
                              hipStream_t stream) {
    const float* x   = (const float*)d_in[0];
    const float* ef  = (const float*)d_in[1];
    const int*   ei  = (const int*)d_in[2];
    const float* W1  = (const float*)d_in[3];
    const float* as1 = (const float*)d_in[4];
    const float* ad1 = (const float*)d_in[5];
    const float* ae1 = (const float*)d_in[6];
    const float* b1  = (const float*)d_in[7];
    const float* eW1 = (const float*)d_in[8];
    const float* W2  = (const float*)d_in[9];
    const float* as2 = (const float*)d_in[10];
    const float* ad2 = (const float*)d_in[11];
    const float* ae2 = (const float*)d_in[12];
    const float* b2  = (const float*)d_in[13];
    const float* eW2 = (const float*)d_in[14];
    float* out = (float*)d_out;
    const int* srcp = ei;
    const int* dstp = ei + NEDGE;

    char* w = (char*)d_ws;
    auto alloc = [&](size_t bytes) -> char* {
        char* r = w;
        w += (bytes + 255) / 256 * 256;
        return r;
    };
    _Float16* hb16  = (_Float16*)alloc((size_t)NNODE * HC * 2);   // h (fp16, both layers)
    _Float16* x216  = (_Float16*)alloc((size_t)NNODE * HC * 2);   // layer-2 GEMM input
    _Float16* wt1   = (_Float16*)alloc((size_t)HC * FIN * 2);     // W1^T fp16
    _Float16* wt2   = (_Float16*)alloc((size_t)HC * HC * 2);      // W2^T fp16
    float* elog1  = (float*)alloc((size_t)NEDGE * 4 * 4);
    float* elog2  = (float*)alloc((size_t)NEDGE * 4 * 4);
    float* pbuf   = (float*)alloc((size_t)NEDGE * 4 * 4);
    float* asrc   = (float*)alloc((size_t)NNODE * 4 * 4);
    float* adst   = (float*)alloc((size_t)NNODE * 4 * 4);
    float* pself  = (float*)alloc((size_t)NNODE * 4 * 4);
    float* webuf1 = (float*)alloc(64 * 4 * 4);
    float* webuf2 = (float*)alloc(64 * 4 * 4);
    int* counts  = (int*)alloc((size_t)NNODE * 4);
    int* offs    = (int*)alloc((size_t)(NNODE + 1) * 4);
    int* tiles   = (int*)alloc(1024 * 4);
    int* cursor  = (int*)alloc((size_t)NNODE * 4);
    int2* es     = (int2*)alloc((size_t)NEDGE * 8);

    hipMemsetAsync(counts, 0, (size_t)NNODE * 4, stream);
    hipMemsetAsync(cursor, 0, (size_t)NNODE * 4, stream);

    // CSR build (shared by both layers)
    k_count<<<(NEDGE + 255) / 256, 256, 0, stream>>>(dstp, counts, NEDGE);
    int nt = (NNODE + SCAN_TILE - 1) / SCAN_TILE;
    k_scan1<<<nt, SCAN_TILE, 0, stream>>>(counts, offs, tiles, NNODE);
    k_scan2<<<1, 64, 0, stream>>>(tiles, nt);
    k_scan3<<<nt, SCAN_TILE, 0, stream>>>(offs, tiles, NNODE, NEDGE);
    k_fill<<<(NEDGE + 255) / 256, 256, 0, stream>>>(srcp, dstp, offs, cursor, es, NEDGE);

    // fp16 weight transposes
    k_castW<<<FIN, 256, 0, stream>>>(W1, wt1, FIN);
    k_castW<<<HC, 256, 0, stream>>>(W2, wt2, HC);

    // edge logits for BOTH layers in one pass over ef
    k_weatt<<<1, 256, 0, stream>>>(eW1, ae1, webuf1);
    k_weatt<<<1, 256, 0, stream>>>(eW2, ae2, webuf2);
    k_elog_both<<<(NEDGE + EB - 1) / EB, EB, 0, stream>>>(ef, webuf1, webuf2, elog1, elog2, NEDGE);

    // ---- layer 1 ----
    k_gemm_mfma<float><<<(NNODE + 63) / 64, 256, 0, stream>>>(x, wt1, hb16, as1, ad1, asrc, adst, NNODE, FIN);
    k_pedge<<<(NNODE + 3) / 4, 256, 0, stream>>>(elog1, asrc, adst, offs, es, pbuf, pself, NNODE);
    k_aggr<1><<<(NNODE + 3) / 4, 256, 0, stream>>>(hb16, pbuf, pself, offs, es, b1, x216, nullptr, NNODE);

    // ---- layer 2 ----
    k_gemm_mfma<_Float16><<<(NNODE + 63) / 64, 256, 0, stream>>>(x216, wt2, hb16, as2, ad2, asrc, adst, NNODE, HC);
    k_pedge<<<(NNODE + 3) / 4, 256, 0, stream>>>(elog2, asrc, adst, offs, es, pbuf, pself, NNODE);
    k_aggr<2><<<(NNODE + 3) / 4, 256, 0, stream>>>(hb16, pbuf, pself, offs, es, b2, nullptr, out, NNODE);
}